// Round 16
// baseline (528.010 us; speedup 1.0000x reference)
//
#include <hip/hip_runtime.h>
#include <math.h>

#define B_ROWS 131072
#define ROWS 128
#define XPB 40   // bf16 pitch for LDS tiles: 80 B rows
#define LP 34    // Ls pitch (f32, scalar access only)

typedef __attribute__((ext_vector_type(8))) short short8v;   // 8 bf16 = MFMA A/B frag
typedef __attribute__((ext_vector_type(4))) float float4v;   // MFMA C/D frag

// ---- precompute M = [Wr*Wp | 0.1*Wr ; Wn*Wp | 0.1*Wn] (f32), c = bias --------
__global__ void precompute_M(const float* __restrict__ Wp,
                             const float* __restrict__ Wr,
                             const float* __restrict__ Wn,
                             const float* __restrict__ bp,
                             const float* __restrict__ br,
                             const float* __restrict__ bn,
                             float* __restrict__ M,
                             float* __restrict__ c) {
  int o = blockIdx.x * 256 + threadIdx.x;          // 32*1024 outputs
  if (o < 32 * 1024) {
    int j = o >> 10, k = o & 1023;
    const float* W = (j < 16) ? Wr : Wn;
    int jj = j & 15;
    float v;
    if (k < 768) {
      double s0 = 0.0, s1 = 0.0, s2 = 0.0, s3 = 0.0;
      for (int d = 0; d < 256; d += 4) {
        s0 += (double)W[jj * 256 + d]     * (double)Wp[(d)     * 768 + k];
        s1 += (double)W[jj * 256 + d + 1] * (double)Wp[(d + 1) * 768 + k];
        s2 += (double)W[jj * 256 + d + 2] * (double)Wp[(d + 2) * 768 + k];
        s3 += (double)W[jj * 256 + d + 3] * (double)Wp[(d + 3) * 768 + k];
      }
      v = (float)((s0 + s1) + (s2 + s3));
    } else {
      v = 0.1f * W[jj * 256 + (k - 768)];
    }
    M[o] = v;
  }
  if (blockIdx.x == 0 && threadIdx.x < 32) {
    int j = threadIdx.x, jj = j & 15;
    const float* W = (j < 16) ? Wr : Wn;
    const float* b = (j < 16) ? br : bn;
    double s = (double)b[jj];
    for (int d = 0; d < 256; ++d)
      s += (double)W[jj * 256 + d] * (double)bp[d];
    c[j] = (float)s;
  }
}

// ------------- main fused kernel (MFMA 3-way-split-bf16 GEMM core) ------------
// r14 verified: 3-way split + per-stage aB f64 fold passes (absmax 0.00195).
// This round: (1) EXACT truncation split (v = h+m+l bit-exact, cheaper pack),
// (2) aS carried in f32 MFMA accumulator across all stages (512x below aB scale),
// (3) 2-stage-ahead A/B register prefetch (load->use > HBM latency).
// All staging in NAMED scalars (round-5/7 lesson: captured arrays spill).

#define LOAD_INTO(S_, X0_, X1_, X2_, X3_, MG_) do {                           \
    const int k0_ = (S_) * 32;                                                \
    const float* src_; int col0_;                                             \
    if (k0_ < 256)      { src_ = zn; col0_ = k0_; }                           \
    else if (k0_ < 512) { src_ = zs; col0_ = k0_ - 256; }                     \
    else if (k0_ < 768) { src_ = zt; col0_ = k0_ - 512; }                     \
    else                { src_ = nz; col0_ = k0_ - 768; }                     \
    const float* base_ = src_ + (size_t)(row0 + sr) * 256 + col0_ + 4 * sk4;  \
    X0_ = *(const float4*)(base_);                                            \
    X1_ = *(const float4*)(base_ + 32 * 256);                                 \
    X2_ = *(const float4*)(base_ + 64 * 256);                                 \
    X3_ = *(const float4*)(base_ + 96 * 256);                                 \
    MG_ = *(const float4*)&M[(size_t)sr * 1024 + k0_ + 4 * sk4];              \
  } while (0)

// exact 3-way truncation split: v = h + m + l bit-exact (8+8+8 mantissa bits);
// all three planes have zero low-16 as f32 patterns -> 2-inst pair packing
#define SPLIT1(V_, H_, M_, L_) do {                                           \
    unsigned u_ = __builtin_bit_cast(unsigned, V_);                           \
    H_ = u_ & 0xFFFF0000u;                                                    \
    float r_ = (V_) - __builtin_bit_cast(float, H_);                          \
    unsigned ru_ = __builtin_bit_cast(unsigned, r_);                          \
    M_ = ru_ & 0xFFFF0000u;                                                   \
    float r2_ = r_ - __builtin_bit_cast(float, M_);                          \
    L_ = __builtin_bit_cast(unsigned, r2_);  /* low16 == 0 by construction */ \
  } while (0)

#define CVT3(VG_, PH_, PM_, PL_, OFF_) do {                                   \
    unsigned h0_,h1_,h2_,h3_,m0_,m1_,m2_,m3_,l0_,l1_,l2_,l3_;                 \
    SPLIT1(VG_.x, h0_, m0_, l0_); SPLIT1(VG_.y, h1_, m1_, l1_);               \
    SPLIT1(VG_.z, h2_, m2_, l2_); SPLIT1(VG_.w, h3_, m3_, l3_);               \
    uint2 ph_, pm_, pl_;                                                      \
    ph_.x = (h0_ >> 16) | h1_;  ph_.y = (h2_ >> 16) | h3_;                    \
    pm_.x = (m0_ >> 16) | m1_;  pm_.y = (m2_ >> 16) | m3_;                    \
    pl_.x = (l0_ >> 16) | l1_;  pl_.y = (l2_ >> 16) | l3_;                    \
    *(uint2*)&PH_[OFF_] = ph_;                                                \
    *(uint2*)&PM_[OFF_] = pm_;                                                \
    *(uint2*)&PL_[OFF_] = pl_;                                                \
  } while (0)

#define WRITE_STAGE(X0_, X1_, X2_, X3_, MG_) do {                             \
    CVT3(X0_, Xh, Xm, Xl, soff);                                              \
    CVT3(X1_, Xh, Xm, Xl, soff + 32 * XPB);                                   \
    CVT3(X2_, Xh, Xm, Xl, soff + 64 * XPB);                                   \
    CVT3(X3_, Xh, Xm, Xl, soff + 96 * XPB);                                   \
    CVT3(MG_, Mhs, Mms, Mls, soff);                                           \
  } while (0)

#define COMPUTE_STAGE() do {                                                  \
    short8v ah0 = *(const short8v*)&Xh[aoff];                                 \
    short8v ah1 = *(const short8v*)&Xh[aoff + 16 * XPB];                      \
    short8v am0 = *(const short8v*)&Xm[aoff];                                 \
    short8v am1 = *(const short8v*)&Xm[aoff + 16 * XPB];                      \
    short8v al0 = *(const short8v*)&Xl[aoff];                                 \
    short8v al1 = *(const short8v*)&Xl[aoff + 16 * XPB];                      \
    short8v bh0 = *(const short8v*)&Mhs[boff];                                \
    short8v bh1 = *(const short8v*)&Mhs[boff + 16 * XPB];                     \
    short8v bm0 = *(const short8v*)&Mms[boff];                                \
    short8v bm1 = *(const short8v*)&Mms[boff + 16 * XPB];                     \
    short8v bl0 = *(const short8v*)&Mls[boff];                                \
    short8v bl1 = *(const short8v*)&Mls[boff + 16 * XPB];                     \
    aB00 = __builtin_amdgcn_mfma_f32_16x16x32_bf16(ah0, bh0, aB00, 0, 0, 0);  \
    aB01 = __builtin_amdgcn_mfma_f32_16x16x32_bf16(ah0, bh1, aB01, 0, 0, 0);  \
    aB10 = __builtin_amdgcn_mfma_f32_16x16x32_bf16(ah1, bh0, aB10, 0, 0, 0);  \
    aB11 = __builtin_amdgcn_mfma_f32_16x16x32_bf16(ah1, bh1, aB11, 0, 0, 0);  \
    aS00 = __builtin_amdgcn_mfma_f32_16x16x32_bf16(ah0, bm0, aS00, 0, 0, 0);  \
    aS01 = __builtin_amdgcn_mfma_f32_16x16x32_bf16(ah0, bm1, aS01, 0, 0, 0);  \
    aS10 = __builtin_amdgcn_mfma_f32_16x16x32_bf16(ah1, bm0, aS10, 0, 0, 0);  \
    aS11 = __builtin_amdgcn_mfma_f32_16x16x32_bf16(ah1, bm1, aS11, 0, 0, 0);  \
    aS00 = __builtin_amdgcn_mfma_f32_16x16x32_bf16(am0, bh0, aS00, 0, 0, 0);  \
    aS01 = __builtin_amdgcn_mfma_f32_16x16x32_bf16(am0, bh1, aS01, 0, 0, 0);  \
    aS10 = __builtin_amdgcn_mfma_f32_16x16x32_bf16(am1, bh0, aS10, 0, 0, 0);  \
    aS11 = __builtin_amdgcn_mfma_f32_16x16x32_bf16(am1, bh1, aS11, 0, 0, 0);  \
    aS00 = __builtin_amdgcn_mfma_f32_16x16x32_bf16(ah0, bl0, aS00, 0, 0, 0);  \
    aS01 = __builtin_amdgcn_mfma_f32_16x16x32_bf16(ah0, bl1, aS01, 0, 0, 0);  \
    aS10 = __builtin_amdgcn_mfma_f32_16x16x32_bf16(ah1, bl0, aS10, 0, 0, 0);  \
    aS11 = __builtin_amdgcn_mfma_f32_16x16x32_bf16(ah1, bl1, aS11, 0, 0, 0);  \
    aS00 = __builtin_amdgcn_mfma_f32_16x16x32_bf16(al0, bh0, aS00, 0, 0, 0);  \
    aS01 = __builtin_amdgcn_mfma_f32_16x16x32_bf16(al0, bh1, aS01, 0, 0, 0);  \
    aS10 = __builtin_amdgcn_mfma_f32_16x16x32_bf16(al1, bh0, aS10, 0, 0, 0);  \
    aS11 = __builtin_amdgcn_mfma_f32_16x16x32_bf16(al1, bh1, aS11, 0, 0, 0);  \
    aS00 = __builtin_amdgcn_mfma_f32_16x16x32_bf16(am0, bm0, aS00, 0, 0, 0);  \
    aS01 = __builtin_amdgcn_mfma_f32_16x16x32_bf16(am0, bm1, aS01, 0, 0, 0);  \
    aS10 = __builtin_amdgcn_mfma_f32_16x16x32_bf16(am1, bm0, aS10, 0, 0, 0);  \
    aS11 = __builtin_amdgcn_mfma_f32_16x16x32_bf16(am1, bm1, aS11, 0, 0, 0);  \
    _Pragma("unroll")                                                         \
    for (int r = 0; r < 4; ++r) {      /* fold aB only (32-k chunk -> f64) */ \
      d00[r] += (double)aB00[r]; aB00[r] = 0.f;                               \
      d01[r] += (double)aB01[r]; aB01[r] = 0.f;                               \
      d10[r] += (double)aB10[r]; aB10[r] = 0.f;                               \
      d11[r] += (double)aB11[r]; aB11[r] = 0.f;                               \
    }                                                                         \
  } while (0)

__global__ __launch_bounds__(256, 3)
void router_main(const float* __restrict__ zn, const float* __restrict__ zs,
                 const float* __restrict__ zt, const float* __restrict__ nz,
                 const float* __restrict__ nr, const int* __restrict__ patches,
                 const float* __restrict__ M, const float* __restrict__ c,
                 float* __restrict__ out) {
  // 37.5 KB carved from one buffer; Ls (17.4 KB f32) aliases Xh/Xm after loop
  __shared__ __align__(16) char smem[38400];
  short* const Xh  = (short*)smem;                 // [128][40] bf16 hi  (10240 B)
  short* const Xm  = (short*)(smem + 10240);       // [128][40] bf16 mid
  short* const Xl  = (short*)(smem + 20480);       // [128][40] bf16 lo
  short* const Mhs = (short*)(smem + 30720);       // [32][40]           (2560 B)
  short* const Mms = (short*)(smem + 33280);       // [32][40]
  short* const Mls = (short*)(smem + 35840);       // [32][40]
  float* const Ls  = (float*)smem;                 // [128][34] f32 alias

  const int t = threadIdx.x;
  const int row0 = blockIdx.x * ROWS;
  const int sr = t >> 3;    // staging row / M row (0..31)
  const int sk4 = t & 7;    // staging k-quad
  const int lane = t & 63;
  const int w = t >> 6;     // wave 0..3 -> rows 32w..32w+31

  // aB folded to f64 per stage; aS (512x smaller scale) rides the MFMA C reg
  float4v aB00 = {0,0,0,0}, aB01 = {0,0,0,0}, aB10 = {0,0,0,0}, aB11 = {0,0,0,0};
  float4v aS00 = {0,0,0,0}, aS01 = {0,0,0,0}, aS10 = {0,0,0,0}, aS11 = {0,0,0,0};
  double d00[4], d01[4], d10[4], d11[4];
#pragma unroll
  for (int r = 0; r < 4; ++r) { d00[r] = 0.0; d01[r] = 0.0; d10[r] = 0.0; d11[r] = 0.0; }

  // 2-stage-ahead register pipeline: A/B buffers, named scalars
  float4 xa0, xa1, xa2, xa3, ma;
  float4 xb0, xb1, xb2, xb3, mb;

  // fragment addresses: A lane = row(lane&15) + kgroup(lane>>4)*8 contiguous k
  const int aoff = (w * 32 + (lane & 15)) * XPB + (lane >> 4) * 8;
  const int boff = (lane & 15) * XPB + (lane >> 4) * 8;
  const int soff = sr * XPB + 4 * sk4;

  LOAD_INTO(0, xa0, xa1, xa2, xa3, ma);   // prologue: stages 0,1 in flight
  LOAD_INTO(1, xb0, xb1, xb2, xb3, mb);

  for (int s = 0; s < 32; s += 2) {
    // ---- even stage: consume A, refill A with s+2 ----
    __syncthreads();   // previous stage's LDS reads done
    WRITE_STAGE(xa0, xa1, xa2, xa3, ma);
    __syncthreads();
    if (s + 2 < 32) LOAD_INTO(s + 2, xa0, xa1, xa2, xa3, ma);
    COMPUTE_STAGE();

    // ---- odd stage: consume B, refill B with s+3 ----
    __syncthreads();
    WRITE_STAGE(xb0, xb1, xb2, xb3, mb);
    __syncthreads();
    if (s + 3 < 32) LOAD_INTO(s + 3, xb0, xb1, xb2, xb3, mb);
    COMPUTE_STAGE();
  }

  __syncthreads();   // all frag reads complete before Ls (aliased) is written

  // C/D layout (m89-verified): col = lane&15 (= j from B), row = (lane>>4)*4+reg
  {
    const double c0 = (double)c[lane & 15];
    const double c1 = (double)c[16 + (lane & 15)];
    const int er = w * 32 + (lane >> 4) * 4;
    const int jc = lane & 15;
#pragma unroll
    for (int reg = 0; reg < 4; ++reg) {
      Ls[(er + reg) * LP + jc]           = (float)(d00[reg] + (double)aS00[reg] + c0);
      Ls[(er + reg) * LP + 16 + jc]      = (float)(d01[reg] + (double)aS01[reg] + c1);
      Ls[(er + 16 + reg) * LP + jc]      = (float)(d10[reg] + (double)aS10[reg] + c0);
      Ls[(er + 16 + reg) * LP + 16 + jc] = (float)(d11[reg] + (double)aS11[reg] + c1);
    }
  }
  __syncthreads();

  if (t < ROWS) {
    const int row = row0 + t;
    float L[32];
#pragma unroll
    for (int j = 0; j < 32; ++j) L[j] = Ls[t * LP + j];

    float nrv[16];
#pragma unroll
    for (int q = 0; q < 4; ++q) {
      float4 v = *(const float4*)&nr[(size_t)row * 16 + 4 * q];
      nrv[4 * q] = v.x; nrv[4 * q + 1] = v.y; nrv[4 * q + 2] = v.z; nrv[4 * q + 3] = v.w;
    }

    float lg[16];
#pragma unroll
    for (int p = 0; p < 16; ++p) {
      const float x = L[16 + p];
      const float sp = (x > 15.f) ? x : log1pf(expf(x));   // softplus
      lg[p] = L[p] + nrv[p] * sp;
    }

    float mx = lg[0];
#pragma unroll
    for (int p = 1; p < 16; ++p) mx = fmaxf(mx, lg[p]);
    float e[16]; float sum = 0.f;
#pragma unroll
    for (int p = 0; p < 16; ++p) { e[p] = expf(lg[p] - mx); sum += e[p]; }
    float w2[16];
#pragma unroll
    for (int p = 0; p < 16; ++p) w2[p] = e[p] / sum;

    // top-4, strict > scan => lowest index wins ties (jax.lax.top_k semantics)
    int idx[4]; float val[4]; unsigned used = 0;
#pragma unroll
    for (int kk = 0; kk < 4; ++kk) {
      float best = -1.f; int bi = 0;
#pragma unroll
      for (int p = 0; p < 16; ++p) {
        const bool ok = (((used >> p) & 1u) == 0u) && (w2[p] > best);
        best = ok ? w2[p] : best;
        bi = ok ? p : bi;
      }
      idx[kk] = bi; val[kk] = best; used |= (1u << bi);
    }

    float so[16];
#pragma unroll
    for (int p = 0; p < 16; ++p) {
      float v = 0.f;
#pragma unroll
      for (int kk = 0; kk < 4; ++kk) v = (idx[kk] == p) ? val[kk] : v;
      so[p] = v;
    }
#pragma unroll
    for (int q = 0; q < 4; ++q)
      *(float4*)&out[(size_t)row * 16 + 4 * q] =
          make_float4(so[4 * q], so[4 * q + 1], so[4 * q + 2], so[4 * q + 3]);

    float4 pv, iv;
    pv.x = (float)patches[idx[0]]; pv.y = (float)patches[idx[1]];
    pv.z = (float)patches[idx[2]]; pv.w = (float)patches[idx[3]];
    iv.x = (float)idx[0]; iv.y = (float)idx[1];
    iv.z = (float)idx[2]; iv.w = (float)idx[3];
    *(float4*)&out[(size_t)B_ROWS * 16 + (size_t)row * 4] = pv;
    *(float4*)&out[(size_t)B_ROWS * 20 + (size_t)row * 4] = iv;
  }
}

// ---------------- launcher ---------------------------------------------------
extern "C" void kernel_launch(void* const* d_in, const int* in_sizes, int n_in,
                              void* d_out, int out_size, void* d_ws, size_t ws_size,
                              hipStream_t stream) {
  const float* zn = (const float*)d_in[0];
  const float* zs = (const float*)d_in[1];
  const float* zt = (const float*)d_in[2];
  const float* nz = (const float*)d_in[3];
  const float* nr = (const float*)d_in[4];
  const int*   pc = (const int*)d_in[5];
  const float* Wp = (const float*)d_in[6];
  const float* bp = (const float*)d_in[7];
  const float* Wr = (const float*)d_in[8];
  const float* br = (const float*)d_in[9];
  const float* Wn = (const float*)d_in[10];
  const float* bn = (const float*)d_in[11];
  float* out = (float*)d_out;
  float* M = (float*)d_ws;            // 32*1024 floats (128 KB, known-safe ws size)
  float* c = M + 32 * 1024;           // 32 floats

  precompute_M<<<128, 256, 0, stream>>>(Wp, Wr, Wn, bp, br, bn, M, c);
  router_main<<<B_ROWS / ROWS, 256, 0, stream>>>(zn, zs, zt, nz, nr, pc, M, c, out);
}